// Round 3
// baseline (472.101 us; speedup 1.0000x reference)
//
#include <hip/hip_runtime.h>

#define BB 4096      // batch rows
#define DD 1024      // feature dim
#define RTS (BB + 16) // padded per-scale stride for rt (avoid OOB eager load)

typedef float f32x16 __attribute__((ext_vector_type(16)));
typedef short bf16x8 __attribute__((ext_vector_type(8)));

__device__ __forceinline__ unsigned short f2bf(float f) {
  unsigned u = __float_as_uint(f);
  unsigned r = u + 0x7fffu + ((u >> 16) & 1u);
  return (unsigned short)(r >> 16);
}

__device__ __forceinline__ void async16(const void* g, void* l) {
  __builtin_amdgcn_global_load_lds(
      (const __attribute__((address_space(1))) void*)g,
      (__attribute__((address_space(3))) void*)l,
      16, 0, 0);
}

// ---- Phase 1: normalize anchor (y==0) / gather+normalize centroids (y=1..3) -> bf16 ----
__global__ __launch_bounds__(256) void prep(
    const float* __restrict__ anchor,
    const int* __restrict__ index,
    const int* __restrict__ i2c0, const int* __restrict__ i2c1, const int* __restrict__ i2c2,
    const float* __restrict__ c0, const float* __restrict__ c1, const float* __restrict__ c2,
    const float* __restrict__ d0, const float* __restrict__ d1, const float* __restrict__ d2,
    unsigned short* __restrict__ a16, unsigned short* __restrict__ p16,
    float* __restrict__ rt, float* __restrict__ rowacc) {
  __shared__ float sred[4];
  const int j = blockIdx.x;
  const int y = blockIdx.y;
  const int tid = threadIdx.x;
  const float* srcrow;
  unsigned short* dstrow;
  if (y == 0) {
    srcrow = anchor + (size_t)j * DD;
    dstrow = a16 + (size_t)j * DD;
  } else {
    const int s = y - 1;
    const int* i2c = (s == 0) ? i2c0 : (s == 1) ? i2c1 : i2c2;
    const float* cent = (s == 0) ? c0 : (s == 1) ? c1 : c2;
    const float* dens = (s == 0) ? d0 : (s == 1) ? d1 : d2;
    const int pid = i2c[index[j]];
    srcrow = cent + (size_t)pid * DD;
    dstrow = p16 + ((size_t)s * BB + j) * DD;
    if (tid == 0) rt[(size_t)s * RTS + j] = 1.0f / dens[pid];
    if (tid == 1) rowacc[(size_t)s * BB + j] = 0.0f;
  }
  const float4 v = ((const float4*)srcrow)[tid];
  float ss = v.x * v.x + v.y * v.y + v.z * v.z + v.w * v.w;
#pragma unroll
  for (int off = 32; off > 0; off >>= 1) ss += __shfl_xor(ss, off, 64);
  if ((tid & 63) == 0) sred[tid >> 6] = ss;
  __syncthreads();
  const float tot = sred[0] + sred[1] + sred[2] + sred[3];
  const float inv = 1.0f / fmaxf(sqrtf(tot), 1e-12f);
  ushort4 o;
  o.x = f2bf(v.x * inv);
  o.y = f2bf(v.y * inv);
  o.z = f2bf(v.z * inv);
  o.w = f2bf(v.w * inv);
  ((ushort4*)dstrow)[tid] = o;
}

// -------- Phase 2: fused sim-GEMM (32x32x16 MFMA, XOR-swizzled LDS) + exp-sum epilogue --------
// LDS layout: slot(row,kpos) at byte addr (row*4 + kpos)*16, kpos = kseg ^ (row&3).
// Staging picks the swizzled global kseg per lane so the mandatory contiguous
// base+lane*16 LDS write produces this layout; global stays 64B-line coalesced.
__global__ __launch_bounds__(256) void gemm_ce_fused(const unsigned short* __restrict__ A,
                                                     const unsigned short* __restrict__ P,
                                                     const float* __restrict__ rt,
                                                     float* __restrict__ rowacc,
                                                     float* __restrict__ diag) {
  __shared__ __align__(16) unsigned short lA[128 * 32];
  __shared__ __align__(16) unsigned short lB[128 * 32];
  __shared__ float rowsum[2][128];
  const int tid = threadIdx.x;
  const int lane = tid & 63;
  const int wave = tid >> 6;
  const int m0 = blockIdx.y * 128;
  const int n0 = blockIdx.x * 128;
  const int s = blockIdx.z;
  const unsigned short* Bm = P + (size_t)s * BB * DD;
  const float* rt_s = rt + (size_t)s * RTS;

  f32x16 acc[2][2];
#pragma unroll
  for (int tm = 0; tm < 2; ++tm)
#pragma unroll
    for (int tn = 0; tn < 2; ++tn)
#pragma unroll
      for (int e = 0; e < 16; ++e) acc[tm][tn][e] = 0.f;

  // staging geometry (per lane, constant across iters):
  const int srow = lane >> 2;                          // row within 16-row chunk
  const int kseg = (lane & 3) ^ ((lane >> 2) & 3);     // swizzled k-segment (8 bf16)

  // wave tile origin
  const int wm = (wave >> 1) * 64;
  const int wn = (wave & 1) * 64;
  const int r31 = lane & 31;
  const int h = lane >> 5;

  for (int k0 = 0; k0 < DD; k0 += 32) {
#pragma unroll
    for (int cc = 0; cc < 2; ++cc) {
      const int chunk = wave * 2 + cc;                 // 0..7, wave-uniform
      const int row = chunk * 16 + srow;               // 0..127
      const unsigned short* ga = A + (size_t)(m0 + row) * DD + k0 + kseg * 8;
      const unsigned short* gb = Bm + (size_t)(n0 + row) * DD + k0 + kseg * 8;
      async16(ga, &lA[chunk * 512]);
      async16(gb, &lB[chunk * 512]);
    }
    __syncthreads();

#pragma unroll
    for (int ks = 0; ks < 2; ++ks) {
      const int kl = ks * 2 + h;                       // logical k-segment for this lane
      bf16x8 af[2], bfr[2];
#pragma unroll
      for (int tm = 0; tm < 2; ++tm) {
        const int row = wm + tm * 32 + r31;
        const int kpos = kl ^ (row & 3);
        af[tm] = *(const bf16x8*)&lA[row * 32 + kpos * 8];
      }
#pragma unroll
      for (int tn = 0; tn < 2; ++tn) {
        const int row = wn + tn * 32 + r31;
        const int kpos = kl ^ (row & 3);
        bfr[tn] = *(const bf16x8*)&lB[row * 32 + kpos * 8];
      }
#pragma unroll
      for (int tm = 0; tm < 2; ++tm)
#pragma unroll
        for (int tn = 0; tn < 2; ++tn)
          acc[tm][tn] = __builtin_amdgcn_mfma_f32_32x32x16_bf16(af[tm], bfr[tn], acc[tm][tn], 0, 0, 0);
    }
    __syncthreads();
  }

  // ---- fused epilogue ----
  // 32x32 C layout: col = lane&31, row_local = (reg&3) + 8*(reg>>2) + 4*(lane>>5)
  const float rt0 = rt_s[0];
  float rtc[2], rtp[2];
#pragma unroll
  for (int tn = 0; tn < 2; ++tn) {
    const int col = n0 + wn + tn * 32 + r31;
    rtc[tn] = rt_s[col];
    rtp[tn] = rt_s[col + 1];   // padded stride makes col+1 safe
  }
#pragma unroll
  for (int tm = 0; tm < 2; ++tm) {
#pragma unroll
    for (int rg = 0; rg < 16; ++rg) {
      const int rloc = (rg & 3) + 8 * (rg >> 2) + 4 * h;
      const int grow = m0 + wm + tm * 32 + rloc;
      float esum = 0.f;
#pragma unroll
      for (int tn = 0; tn < 2; ++tn) {
        const int col = n0 + wn + tn * 32 + r31;
        const float v = acc[tm][tn][rg];
        const float rr = (col == grow) ? rt0 : ((col < grow) ? rtp[tn] : rtc[tn]);
        const float l = v * rr;
        if (col == grow) diag[(size_t)s * BB + grow] = l;
        esum += __expf(l);
      }
      // reduce across the 32 lanes holding this row's 32 cols (bit5 preserved)
#pragma unroll
      for (int off = 1; off < 32; off <<= 1) esum += __shfl_xor(esum, off, 64);
      if (r31 == 0) rowsum[wave & 1][wm + tm * 32 + rloc] = esum;
    }
  }
  __syncthreads();
  for (int t = tid; t < 128; t += 256)
    atomicAdd(&rowacc[(size_t)s * BB + m0 + t], rowsum[0][t] + rowsum[1][t]);
}

// ---------------- Phase 3: loss = sum_s w_s * (log(sumexp_s) - diag_s) ----------------
__global__ __launch_bounds__(256) void finish(const float* __restrict__ rowacc,
                                              const float* __restrict__ diag,
                                              float* __restrict__ out) {
  const int i = blockIdx.x * 256 + threadIdx.x;
  const float ce0 = logf(rowacc[i]) - diag[i];
  const float ce1 = logf(rowacc[BB + i]) - diag[BB + i];
  const float ce2 = logf(rowacc[2 * BB + i]) - diag[2 * BB + i];
  out[i] = ce0 * (1.0f / 27.0f) + ce1 * (1.0f / 9.0f) + ce2 * (1.0f / 3.0f);
}

extern "C" void kernel_launch(void* const* d_in, const int* in_sizes, int n_in,
                              void* d_out, int out_size, void* d_ws, size_t ws_size,
                              hipStream_t stream) {
  const float* anchor = (const float*)d_in[0];
  const int* index    = (const int*)d_in[1];
  const int* i2c0     = (const int*)d_in[2];
  const float* c0     = (const float*)d_in[3];
  const float* de0    = (const float*)d_in[4];
  const int* i2c1     = (const int*)d_in[5];
  const float* c1     = (const float*)d_in[6];
  const float* de1    = (const float*)d_in[7];
  const int* i2c2     = (const int*)d_in[8];
  const float* c2     = (const float*)d_in[9];
  const float* de2    = (const float*)d_in[10];

  char* ws = (char*)d_ws;
  const size_t A16_OFF = 0;                                      // 8 MB
  const size_t P16_OFF = A16_OFF + (size_t)BB * DD * 2;          // 24 MB (3 scales)
  const size_t RT_OFF  = P16_OFF + (size_t)3 * BB * DD * 2;      // 3*RTS floats
  const size_t ACC_OFF = RT_OFF + (size_t)3 * RTS * 4;           // 48 KB
  const size_t DIA_OFF = ACC_OFF + (size_t)3 * BB * 4;           // 48 KB

  unsigned short* a16 = (unsigned short*)(ws + A16_OFF);
  unsigned short* p16 = (unsigned short*)(ws + P16_OFF);
  float* rt     = (float*)(ws + RT_OFF);
  float* rowacc = (float*)(ws + ACC_OFF);
  float* diag   = (float*)(ws + DIA_OFF);
  float* out = (float*)d_out;

  prep<<<dim3(BB, 4), 256, 0, stream>>>(anchor, index, i2c0, i2c1, i2c2,
                                        c0, c1, c2, de0, de1, de2,
                                        a16, p16, rt, rowacc);
  gemm_ce_fused<<<dim3(BB / 128, BB / 128, 3), 256, 0, stream>>>(a16, p16, rt, rowacc, diag);
  finish<<<BB / 256, 256, 0, stream>>>(rowacc, diag, out);
}